// Round 4
// baseline (1126.644 us; speedup 1.0000x reference)
//
#include <hip/hip_runtime.h>
#include <stdint.h>

// ---------------------------------------------------------------------------
// RGNN layer: h_t = relu( sum_k L^{k+1} (x_t W_k + h_{t-1} H_k) ), h_{-1}=0
// B=8 T=16 N=1024 F=128 K=4.
//
//   Lcat [1024 n][4096 q],  q=(k,m):  Lcat[n][k*1024+m] = (L^{k+1})[n][m]
//   S    [(b,g) c][4096 q]          : S[c][q] = (x_t W_k + h H_k)[b,m,g]
//   Z[n][c] = sum_q Lcat[n][q] * S[c][q]   (S stored as B^T)
//   h[b][n][g] = relu(Z),  out[b][t][n][g] = h
//
// GEMMs are REGISTER-DIRECT (no LDS, no barriers): each wave loads its MFMA
// fragments straight from global (L2-resident operands) into double-buffered
// VGPRs. Within a block every A-row/B-col belongs to exactly one wave, so
// LDS staging would provide zero dedup — it was pure LDS-BW cost (~7.5us/CU
// per graph dispatch). Bijective XCD swizzle clusters each split-K slice on
// one XCD (3 MB working set -> L2-fit).
// ---------------------------------------------------------------------------

typedef __bf16 bf16_t;
typedef __bf16 bf16x4 __attribute__((ext_vector_type(4)));
typedef __bf16 bf16x8 __attribute__((ext_vector_type(8)));
typedef float  f32x4  __attribute__((ext_vector_type(4)));

// ---- setup kernels --------------------------------------------------------

__global__ void k_convert_x(const float* __restrict__ xin,
                            bf16_t* __restrict__ xb, int n4) {
    int i = blockIdx.x * 256 + threadIdx.x;
    int stride = gridDim.x * 256;
    for (; i < n4; i += stride) {
        float4 v = reinterpret_cast<const float4*>(xin)[i];
        bf16x4 o = { (bf16_t)v.x, (bf16_t)v.y, (bf16_t)v.z, (bf16_t)v.w };
        reinterpret_cast<bf16x4*>(xb)[i] = o;
    }
}

__global__ void k_setup_L(const float* __restrict__ L,
                          bf16_t* __restrict__ Lcat,   // [1024][4096], block 0
                          bf16_t* __restrict__ Lt) {   // [1024][1024] = L^T
    int idx = blockIdx.x * 256 + threadIdx.x;          // 1024*1024 threads
    int n = idx >> 10, m = idx & 1023;
    float v = L[idx];
    Lcat[n * 4096 + m] = (bf16_t)v;
    Lt[m * 1024 + n]   = (bf16_t)v;
}

__global__ void k_setup_WH(const float* __restrict__ W,
                           const float* __restrict__ H,
                           bf16_t* __restrict__ WHT) { // [4][128 g][256 f]
    int idx = blockIdx.x * 256 + threadIdx.x;          // 4*128*128 threads
    int k = idx >> 14, f = (idx >> 7) & 127, g = idx & 127;
    WHT[(k * 128 + g) * 256 + f]       = (bf16_t)W[idx];
    WHT[(k * 128 + g) * 256 + 128 + f] = (bf16_t)H[idx];
}

// ---- combine: Z = relu(sum_z Zpart[z]) -> h bf16, out f32 ------------------

__global__ __launch_bounds__(256)
void k_combine(const float* __restrict__ Zp,   // [4][1024][1024] (n, c=(b,g))
               bf16_t* __restrict__ h, float* __restrict__ out, int t) {
    int i = blockIdx.x * 256 + threadIdx.x;    // 262144 threads, 4 f32 each
    int n  = i >> 8;
    int cg = (i & 255) * 4;                    // c base (4-aligned, within b)
    size_t o = (size_t)n * 1024 + cg;
    float4 v0 = *reinterpret_cast<const float4*>(Zp + o);
    float4 v1 = *reinterpret_cast<const float4*>(Zp + 1048576 + o);
    float4 v2 = *reinterpret_cast<const float4*>(Zp + 2097152 + o);
    float4 v3 = *reinterpret_cast<const float4*>(Zp + 3145728 + o);
    float4 s;
    s.x = fmaxf(v0.x + v1.x + v2.x + v3.x, 0.f);
    s.y = fmaxf(v0.y + v1.y + v2.y + v3.y, 0.f);
    s.z = fmaxf(v0.z + v1.z + v2.z + v3.z, 0.f);
    s.w = fmaxf(v0.w + v1.w + v2.w + v3.w, 0.f);
    int b = cg >> 7, g = cg & 127;
    size_t ho = (size_t)b * 131072 + (size_t)n * 128 + g;
    bf16x4 hb = { (bf16_t)s.x, (bf16_t)s.y, (bf16_t)s.z, (bf16_t)s.w };
    *reinterpret_cast<bf16x4*>(h + ho) = hb;
    *reinterpret_cast<float4*>(out + (size_t)b * 2097152
                                   + (size_t)t * 131072
                                   + (size_t)n * 128 + g) = s;
}

// ---- register-direct GEMM template ----------------------------------------
// C[M][N] = A[M][KTOT] @ B[KTOT][N], B given as B^T rows (N rows, K contig).
// Grid: 1D NWG = GX*GY*GZ (each a multiple meeting NWG%8==0), bijective XCD
// swizzle, decode DEC: 0 = x fast / z slow (graph, chain), 1 = (y,z) fast /
// x slow (feature — clusters c-columns per XCD).
// EPI: 0 = plain bf16 C     1 = S-layout bf16     2 = relu h+out    3 = f32
// partial Zpart[bz].   BADDR: 0 = BT rows; 1 = feature split x|h.
// ZK: per-bz K offset (split-K) — 0 means bz is the tap index instead.
template<int BM, int BN, int GX, int GY, int GZ, int KTOT,
         int EPI, int BADDR, int ZK, int DEC>
__global__ __launch_bounds__(256)
void k_gemm(const bf16_t* __restrict__ A, int lda,
            const bf16_t* __restrict__ BT, int ldbt,
            const bf16_t* __restrict__ B2,
            bf16_t* __restrict__ Cb, float* __restrict__ Cf,
            int ldc, int t)
{
    constexpr int BK = 64;
    constexpr int WM = BM / 2, WN = BN / 2;
    constexpr int MF = WM / 16, NF = WN / 16;
    constexpr int NT = KTOT / BK;               // even for all instantiations
    constexpr int NWG = GX * GY * GZ;

    const int tid  = threadIdx.x;
    const int lane = tid & 63;
    const int wave = tid >> 6;
    const int wm = wave >> 1, wn = wave & 1;    // 2x2 wave grid

    // bijective XCD swizzle (NWG % 8 == 0): XCD k owns swz chunk k*(NWG/8)..
    const int id  = blockIdx.x;
    const int swz = (id & 7) * (NWG / 8) + (id >> 3);
    int bx, by, bz;
    if (DEC == 0) {
        bx = swz % GX; by = (swz / GX) % GY; bz = swz / (GX * GY);
    } else {
        by = swz % GY; bz = (swz / GY) % GZ; bx = swz / (GY * GZ);
    }

    const int m0 = by * BM;
    const int c0 = bx * BN;
    const int kb_ = bz;                         // tap index OR split-K slice

    const bf16_t* Ap = (EPI == 1) ? (A + kb_ * 128 * 256) : A;
    const int q0base = (ZK > 0) ? kb_ * ZK : 0;

    const int lane15 = lane & 15;
    const int ksub   = (lane >> 4) * 8;         // k-element offset per lane grp

    // per-fragment element offsets (uniform bases + 32-bit v-offsets)
    uint32_t offA[MF];
    #pragma unroll
    for (int mf = 0; mf < MF; ++mf) {
        uint32_t row = (uint32_t)(m0 + wm * WM + mf * 16 + lane15);
        offA[mf] = row * (uint32_t)lda + (uint32_t)(q0base + ksub);
    }
    uint32_t offB[NF], offBx[NF], offBh[NF];
    #pragma unroll
    for (int nf = 0; nf < NF; ++nf) {
        uint32_t c = (uint32_t)(c0 + wn * WN + nf * 16 + lane15);
        if (BADDR == 0) {
            offB[nf] = c * (uint32_t)ldbt + (uint32_t)(q0base + ksub);
            offBx[nf] = 0; offBh[nf] = 0;
        } else {
            offB[nf] = 0;
            offBx[nf] = (c >> 10) * 2097152u + (uint32_t)t * 131072u
                      + (c & 1023u) * 128u + (uint32_t)ksub;
            offBh[nf] = c * 128u + (uint32_t)ksub;
        }
    }

    auto ldA = [&](int mf, int tile, int kk) -> bf16x8 {
        return *reinterpret_cast<const bf16x8*>(
            Ap + offA[mf] + (uint32_t)(tile * 64 + kk * 32));
    };
    auto ldB = [&](int nf, int tile, int kk) -> bf16x8 {
        if constexpr (BADDR == 0) {
            return *reinterpret_cast<const bf16x8*>(
                BT + offB[nf] + (uint32_t)(tile * 64 + kk * 32));
        } else {
            if (tile < NT / 2)                   // x side (f in [0,128))
                return *reinterpret_cast<const bf16x8*>(
                    BT + offBx[nf] + (uint32_t)(tile * 64 + kk * 32));
            return *reinterpret_cast<const bf16x8*>(   // h side
                B2 + offBh[nf] + (uint32_t)((tile - NT / 2) * 64 + kk * 32));
        }
    };

    f32x4 acc[MF][NF] = {};
    bf16x8 a0[MF][2], b0[NF][2], a1[MF][2], b1[NF][2];

    auto loadT = [&](bf16x8 (&fa)[MF][2], bf16x8 (&fb)[NF][2], int tile) {
        #pragma unroll
        for (int kk = 0; kk < 2; ++kk) {
            #pragma unroll
            for (int mf = 0; mf < MF; ++mf) fa[mf][kk] = ldA(mf, tile, kk);
            #pragma unroll
            for (int nf = 0; nf < NF; ++nf) fb[nf][kk] = ldB(nf, tile, kk);
        }
    };
    auto mfmaT = [&](bf16x8 (&fa)[MF][2], bf16x8 (&fb)[NF][2]) {
        #pragma unroll
        for (int kk = 0; kk < 2; ++kk)
            #pragma unroll
            for (int mf = 0; mf < MF; ++mf)
                #pragma unroll
                for (int nf = 0; nf < NF; ++nf)
                    acc[mf][nf] = __builtin_amdgcn_mfma_f32_16x16x32_bf16(
                        fa[mf][kk], fb[nf][kk], acc[mf][nf], 0, 0, 0);
    };

    // register double-buffered pipeline: no LDS, no barriers.
    loadT(a0, b0, 0);
    for (int kt = 0; kt < NT; kt += 2) {
        loadT(a1, b1, kt + 1);
        mfmaT(a0, b0);
        if (kt + 2 < NT) loadT(a0, b0, kt + 2);
        mfmaT(a1, b1);
    }

    // epilogue: D lane map col=lane&15, row=(lane>>4)*4+r  [m89-verified]
    #pragma unroll
    for (int mf = 0; mf < MF; ++mf) {
        #pragma unroll
        for (int nf = 0; nf < NF; ++nf) {
            f32x4 v = acc[mf][nf];
            int col   = c0 + wn * WN + nf * 16 + lane15;
            int rbase = m0 + wm * WM + mf * 16 + ((lane >> 4) * 4);
            #pragma unroll
            for (int r = 0; r < 4; ++r) {
                int row = rbase + r;
                float val = v[r];
                if (EPI == 0) {
                    Cb[(size_t)row * ldc + col] = (bf16_t)val;
                } else if (EPI == 1) {
                    // S[b][g][k][m]: col=(b,m), row=g
                    Cb[(size_t)(col >> 10) * 524288 + (size_t)row * 4096
                       + (size_t)kb_ * 1024 + (col & 1023)] = (bf16_t)val;
                } else if (EPI == 2) {
                    val = fmaxf(val, 0.f);
                    int b = col >> 7, g = col & 127;   // col=(b,g), row=n
                    Cb[(size_t)b * 131072 + (size_t)row * 128 + g] = (bf16_t)val;
                    Cf[(size_t)b * 2097152 + (size_t)t * 131072
                       + (size_t)row * 128 + g] = val;
                } else {
                    // f32 partial: Zpart[kb_][row n][col c]
                    Cf[(size_t)kb_ * 1048576 + (size_t)row * 1024 + col] = val;
                }
            }
        }
    }
}

// ---- launch ---------------------------------------------------------------

extern "C" void kernel_launch(void* const* d_in, const int* in_sizes, int n_in,
                              void* d_out, int out_size, void* d_ws, size_t ws_size,
                              hipStream_t stream) {
    const float* x = (const float*)d_in[0];   // [8][16][1024][128]
    const float* L = (const float*)d_in[1];   // [1024][1024]
    const float* W = (const float*)d_in[2];   // [4][128][128]
    const float* H = (const float*)d_in[3];   // [4][128][128]
    float* out = (float*)d_out;               // [8][16][1024][128]

    char* ws = (char*)d_ws;
    bf16_t* xb   = (bf16_t*)(ws);              // 33,554,432 B
    bf16_t* Lcat = (bf16_t*)(ws + 33554432);   //  8,388,608 B [1024][4096]
    bf16_t* Lt   = (bf16_t*)(ws + 41943040);   //  2,097,152 B
    bf16_t* WHT  = (bf16_t*)(ws + 44040192);   //    262,144 B
    bf16_t* Sbuf = (bf16_t*)(ws + 44302336);   //  8,388,608 B [1024][4096]
    bf16_t* h    = (bf16_t*)(ws + 52690944);   //  2,097,152 B [8][1024][128]
    float*  Zp   = (float*) (ws + 54788096);   // 16,777,216 B [4][1024][1024]
    if (ws_size < 54788096u) return;
    const bool bigws = (ws_size >= 71565312u);

    hipMemsetAsync(h, 0, 2097152, stream);
    k_convert_x<<<4096, 256, 0, stream>>>(x, xb, 16777216 / 4);
    k_setup_L <<<4096, 256, 0, stream>>>(L, Lcat, Lt);
    k_setup_WH<<<256, 256, 0, stream>>>(W, H, WHT);

    // L-power chain: block p = block(p-1) @ L (M=N=K=1024), 256 WGs
    for (int p = 1; p < 4; ++p) {
        k_gemm<64, 64, 16, 16, 1, 1024, 0, 0, 0, 0><<<256, 256, 0, stream>>>(
            Lcat + (p - 1) * 1024, 4096, Lt, 1024, nullptr,
            Lcat + p * 1024, nullptr, 4096, 0);
    }

    for (int t = 0; t < 16; ++t) {
        // feature: S_k = WHT_k @ [x_t | h]^T  (M=128,N=8192,K=256), 512 WGs
        k_gemm<64, 128, 64, 2, 4, 256, 1, 1, 0, 1><<<512, 256, 0, stream>>>(
            WHT, 256, xb, 0, h,
            Sbuf, nullptr, 0, t);
        if (bigws) {
            // graph: Zpart[z] = Lcat[:,z*1024:+1024] @ S[z], split-K=4, 512 WGs
            k_gemm<64, 128, 8, 16, 4, 1024, 3, 0, 1024, 0><<<512, 256, 0, stream>>>(
                Lcat, 4096, Sbuf, 4096, nullptr,
                nullptr, Zp, 0, t);
            k_combine<<<1024, 256, 0, stream>>>(Zp, h, out, t);
        } else {
            // fallback: single-dispatch graph GEMM (128 WGs)
            k_gemm<64, 128, 8, 16, 1, 4096, 2, 0, 0, 0><<<128, 256, 0, stream>>>(
                Lcat, 4096, Sbuf, 4096, nullptr,
                h, out, 0, t);
        }
    }
}

// Round 5
// 558.907 us; speedup vs baseline: 2.0158x; 2.0158x over previous
//
#include <hip/hip_runtime.h>
#include <stdint.h>

// ---------------------------------------------------------------------------
// RGNN layer: h_t = relu( sum_k L^{k+1} (x_t W_k + h_{t-1} H_k) ), h_{-1}=0
// B=8 T=16 N=1024 F=128 K=4.
//
//   Lcat [1024 n][4096 q],  q=(k,m):  Lcat[n][k*1024+m] = (L^{k+1})[n][m]
//   S    [(b,g) c][4096 q]          : S[c][q] = (x_t W_k + h H_k)[b,m,g]
//   Z[n][c] = sum_q Lcat[n][q] * S[c][q]   (S stored as B^T)
//   h[b][n][g] = relu(Z),  out[b][t][n][g] = h
//
// GEMM: LDS-staged (mandatory for dedup — round-4 register-direct doubled
// L2/L3 traffic and regressed 2.6x), 2-phase barrier loop (round-3 counted
// vmcnt was neutral), 32x32x16 MFMA with 64x64 wave tiles (halves LDS
// bytes/FLOP vs 32x64 wave tiles: (WM+WN)/(WM*WN) = 0.031 vs 0.047).
// Graph GEMM split-K=8 -> 512 WGs (2 blocks/CU at 64KB LDS), XCD swizzle
// puts one K-slice per XCD (2MB working set, L2-resident).
// ---------------------------------------------------------------------------

typedef __bf16 bf16_t;
typedef __bf16 bf16x4 __attribute__((ext_vector_type(4)));
typedef __bf16 bf16x8 __attribute__((ext_vector_type(8)));
typedef float  f32x4  __attribute__((ext_vector_type(4)));
typedef float  f32x16 __attribute__((ext_vector_type(16)));

__device__ __forceinline__ void gload_lds16(const void* g, void* l) {
    __builtin_amdgcn_global_load_lds(
        (const __attribute__((address_space(1))) void*)g,
        (__attribute__((address_space(3))) void*)l,
        16, 0, 0);
}

// ---- setup kernels --------------------------------------------------------

__global__ void k_convert_x(const float* __restrict__ xin,
                            bf16_t* __restrict__ xb, int n4) {
    int i = blockIdx.x * 256 + threadIdx.x;
    int stride = gridDim.x * 256;
    for (; i < n4; i += stride) {
        float4 v = reinterpret_cast<const float4*>(xin)[i];
        bf16x4 o = { (bf16_t)v.x, (bf16_t)v.y, (bf16_t)v.z, (bf16_t)v.w };
        reinterpret_cast<bf16x4*>(xb)[i] = o;
    }
}

__global__ void k_setup_L(const float* __restrict__ L,
                          bf16_t* __restrict__ Lcat,   // [1024][4096], block 0
                          bf16_t* __restrict__ Lt) {   // [1024][1024] = L^T
    int idx = blockIdx.x * 256 + threadIdx.x;          // 1024*1024 threads
    int n = idx >> 10, m = idx & 1023;
    float v = L[idx];
    Lcat[n * 4096 + m] = (bf16_t)v;
    Lt[m * 1024 + n]   = (bf16_t)v;
}

__global__ void k_setup_WH(const float* __restrict__ W,
                           const float* __restrict__ H,
                           bf16_t* __restrict__ WHT) { // [4][128 g][256 f]
    int idx = blockIdx.x * 256 + threadIdx.x;          // 4*128*128 threads
    int k = idx >> 14, f = (idx >> 7) & 127, g = idx & 127;
    WHT[(k * 128 + g) * 256 + f]       = (bf16_t)W[idx];
    WHT[(k * 128 + g) * 256 + 128 + f] = (bf16_t)H[idx];
}

// ---- combine: Z = relu(sum_z Zpart[z]) -> h bf16, out f32 ------------------

template<int NZ>
__global__ __launch_bounds__(256)
void k_combine(const float* __restrict__ Zp,   // [NZ][1024][1024] (n, c=(b,g))
               bf16_t* __restrict__ h, float* __restrict__ out, int t) {
    int i = blockIdx.x * 256 + threadIdx.x;    // 262144 threads, 4 f32 each
    int n  = i >> 8;
    int cg = (i & 255) * 4;                    // c base (4-aligned, within b)
    size_t o = (size_t)n * 1024 + cg;
    float4 s = *reinterpret_cast<const float4*>(Zp + o);
    #pragma unroll
    for (int z = 1; z < NZ; ++z) {
        float4 v = *reinterpret_cast<const float4*>(Zp + (size_t)z * 1048576 + o);
        s.x += v.x; s.y += v.y; s.z += v.z; s.w += v.w;
    }
    s.x = fmaxf(s.x, 0.f); s.y = fmaxf(s.y, 0.f);
    s.z = fmaxf(s.z, 0.f); s.w = fmaxf(s.w, 0.f);
    int b = cg >> 7, g = cg & 127;
    size_t ho = (size_t)b * 131072 + (size_t)n * 128 + g;
    bf16x4 hb = { (bf16_t)s.x, (bf16_t)s.y, (bf16_t)s.z, (bf16_t)s.w };
    *reinterpret_cast<bf16x4*>(h + ho) = hb;
    *reinterpret_cast<float4*>(out + (size_t)b * 2097152
                                   + (size_t)t * 131072
                                   + (size_t)n * 128 + g) = s;
}

// ---- GEMM template (32x32x16 MFMA, 64x64 wave tiles) -----------------------
// C[M][N] = A[M][KTOT] @ B[KTOT][N], B given as B^T rows (N rows, K contig).
// 4 waves in a 2x2 grid, wave tile (BM/2)x(BN/2), 32x32 fragments.
// Grid 1D = GX*GY*GZ (NWG%8==0), bijective XCD swizzle; DEC=0: x fast/z slow;
// DEC=1: (y,z) fast/x slow.
// EPI: 0 plain bf16   1 S-layout bf16   2 relu h+out   3 f32 partial Zp[bz]
// BADDR: 0 = BT rows; 1 = feature split x|h.   ZK: per-bz K offset.
template<int BM, int BN, int GX, int GY, int GZ, int KTOT,
         int EPI, int BADDR, int ZK, int DEC>
__global__ __launch_bounds__(256)
void k_gemm(const bf16_t* __restrict__ A, int lda,
            const bf16_t* __restrict__ BT, int ldbt,
            const bf16_t* __restrict__ B2,
            bf16_t* __restrict__ Cb, float* __restrict__ Cf,
            int ldc, int t)
{
    constexpr int BK = 64;                 // K-tile; LDS rows are 128 B
    constexpr int WM = BM / 2, WN = BN / 2;
    constexpr int MF = WM / 32, NF = WN / 32;
    constexpr int NT = KTOT / BK;
    constexpr int NWG = GX * GY * GZ;
    constexpr int ACH = BM * 8;            // 16B chunks per A tile
    constexpr int BCH = BN * 8;

    __shared__ __align__(16) bf16_t As[2][BM * BK];
    __shared__ __align__(16) bf16_t Bs[2][BN * BK];

    const int tid  = threadIdx.x;
    const int lane = tid & 63;
    const int wave = tid >> 6;
    const int wm = wave >> 1, wn = wave & 1;     // 2x2 wave grid

    // bijective XCD swizzle (NWG % 8 == 0)
    const int id  = blockIdx.x;
    const int swz = (id & 7) * (NWG / 8) + (id >> 3);
    int bx, by, bz;
    if (DEC == 0) {
        bx = swz % GX; by = (swz / GX) % GY; bz = swz / (GX * GY);
    } else {
        by = swz % GY; bz = (swz / GY) % GZ; bx = swz / (GY * GZ);
    }

    const int m0 = by * BM;
    const int c0 = bx * BN;
    const int kb_ = bz;                          // tap index OR split-K slice

    const bf16_t* Ap = (EPI == 1) ? (A + kb_ * 128 * 256) : A;

    f32x16 acc[MF][NF] = {};

    auto stage = [&](int bufi, int kt) {
        const int q0 = kt * BK + (ZK > 0 ? kb_ * ZK : 0);
        #pragma unroll
        for (int i = 0; i < ACH / 256; ++i) {
            int chunk = i * 256 + tid;
            int off = chunk * 16;                       // byte off in tile
            int row = off >> 7;                         // 128B rows
            int kel = ((off ^ ((row & 7) << 4)) & 127) >> 1; // inv-swizzled k
            const bf16_t* src = Ap + (size_t)(m0 + row) * lda + (q0 + kel);
            gload_lds16(src, (char*)(&As[bufi][0]) + off);
        }
        #pragma unroll
        for (int i = 0; i < BCH / 256; ++i) {
            int chunk = i * 256 + tid;
            int off = chunk * 16;
            int row = off >> 7;
            int kel = ((off ^ ((row & 7) << 4)) & 127) >> 1;
            int c = c0 + row;
            const bf16_t* src;
            if (BADDR == 0) {
                src = BT + (size_t)c * ldbt + (q0 + kel);
            } else {
                int f = q0 + kel;
                if (q0 < 128) {
                    // x part: xb[B][T][N][F], c=(b,m)
                    src = BT + (size_t)(c >> 10) * 2097152
                             + (size_t)t * 131072
                             + (size_t)(c & 1023) * 128 + f;
                } else {
                    // h part: h[B][N][F] flat, rows are c
                    src = B2 + (size_t)c * 128 + (f - 128);
                }
            }
            gload_lds16(src, (char*)(&Bs[bufi][0]) + off);
        }
    };

    stage(0, 0);
    asm volatile("s_waitcnt vmcnt(0)" ::: "memory");
    __syncthreads();

    for (int kt = 0; kt < NT; ++kt) {
        int cur = kt & 1;
        if (kt + 1 < NT) stage(cur ^ 1, kt + 1);

        // 32x32x16 fragments: A row=lane&31, k=(lane>>5)*8+j
        #pragma unroll
        for (int kk = 0; kk < 4; ++kk) {
            bf16x8 af[MF], bfr[NF];
            const int klane = kk * 32 + (lane >> 5) * 16;  // byte off of k
            #pragma unroll
            for (int mf = 0; mf < MF; ++mf) {
                int row = wm * WM + mf * 32 + (lane & 31);
                int bo = (row * 128 + klane) ^ ((row & 7) << 4);
                af[mf] = *reinterpret_cast<const bf16x8*>(
                             (const char*)(&As[cur][0]) + bo);
            }
            #pragma unroll
            for (int nf = 0; nf < NF; ++nf) {
                int row = wn * WN + nf * 32 + (lane & 31);
                int bo = (row * 128 + klane) ^ ((row & 7) << 4);
                bfr[nf] = *reinterpret_cast<const bf16x8*>(
                              (const char*)(&Bs[cur][0]) + bo);
            }
            #pragma unroll
            for (int mf = 0; mf < MF; ++mf)
                #pragma unroll
                for (int nf = 0; nf < NF; ++nf)
                    acc[mf][nf] = __builtin_amdgcn_mfma_f32_32x32x16_bf16(
                        af[mf], bfr[nf], acc[mf][nf], 0, 0, 0);
        }

        asm volatile("s_waitcnt vmcnt(0)" ::: "memory");
        __syncthreads();
    }

    // epilogue: 32x32 D map col=lane&31, row=(r&3)+8*(r>>2)+4*(lane>>5)
    // [m74/m101-verified]
    #pragma unroll
    for (int mf = 0; mf < MF; ++mf) {
        #pragma unroll
        for (int nf = 0; nf < NF; ++nf) {
            f32x16 v = acc[mf][nf];
            int col   = c0 + wn * WN + nf * 32 + (lane & 31);
            int rbase = m0 + wm * WM + mf * 32 + 4 * (lane >> 5);
            #pragma unroll
            for (int r = 0; r < 16; ++r) {
                int row = rbase + (r & 3) + 8 * (r >> 2);
                float val = v[r];
                if (EPI == 0) {
                    Cb[(size_t)row * ldc + col] = (bf16_t)val;
                } else if (EPI == 1) {
                    // S[b][g][k][m]: col=(b,m), row=g
                    Cb[(size_t)(col >> 10) * 524288 + (size_t)row * 4096
                       + (size_t)kb_ * 1024 + (col & 1023)] = (bf16_t)val;
                } else if (EPI == 2) {
                    val = fmaxf(val, 0.f);
                    int b = col >> 7, g = col & 127;   // col=(b,g), row=n
                    Cb[(size_t)b * 131072 + (size_t)row * 128 + g] = (bf16_t)val;
                    Cf[(size_t)b * 2097152 + (size_t)t * 131072
                       + (size_t)row * 128 + g] = val;
                } else {
                    // f32 partial: Zpart[kb_][row n][col c]
                    Cf[(size_t)kb_ * 1048576 + (size_t)row * 1024 + col] = val;
                }
            }
        }
    }
}

// ---- launch ---------------------------------------------------------------

extern "C" void kernel_launch(void* const* d_in, const int* in_sizes, int n_in,
                              void* d_out, int out_size, void* d_ws, size_t ws_size,
                              hipStream_t stream) {
    const float* x = (const float*)d_in[0];   // [8][16][1024][128]
    const float* L = (const float*)d_in[1];   // [1024][1024]
    const float* W = (const float*)d_in[2];   // [4][128][128]
    const float* H = (const float*)d_in[3];   // [4][128][128]
    float* out = (float*)d_out;               // [8][16][1024][128]

    char* ws = (char*)d_ws;
    bf16_t* xb   = (bf16_t*)(ws);              // 33,554,432 B
    bf16_t* Lcat = (bf16_t*)(ws + 33554432);   //  8,388,608 B [1024][4096]
    bf16_t* Lt   = (bf16_t*)(ws + 41943040);   //  2,097,152 B
    bf16_t* WHT  = (bf16_t*)(ws + 44040192);   //    262,144 B
    bf16_t* Sbuf = (bf16_t*)(ws + 44302336);   //  8,388,608 B [1024][4096]
    bf16_t* h    = (bf16_t*)(ws + 52690944);   //  2,097,152 B [8][1024][128]
    float*  Zp   = (float*) (ws + 54788096);   // 33,554,432 B [8][1024][1024]
    if (ws_size < 54788096u) return;
    const bool bigws = (ws_size >= 88342528u);

    hipMemsetAsync(h, 0, 2097152, stream);
    k_convert_x<<<4096, 256, 0, stream>>>(x, xb, 16777216 / 4);
    k_setup_L <<<4096, 256, 0, stream>>>(L, Lcat, Lt);
    k_setup_WH<<<256, 256, 0, stream>>>(W, H, WHT);

    // L-power chain: block p = block(p-1) @ L (M=N=K=1024), 256 WGs
    for (int p = 1; p < 4; ++p) {
        k_gemm<64, 64, 16, 16, 1, 1024, 0, 0, 0, 0><<<256, 256, 0, stream>>>(
            Lcat + (p - 1) * 1024, 4096, Lt, 1024, nullptr,
            Lcat + p * 1024, nullptr, 4096, 0);
    }

    for (int t = 0; t < 16; ++t) {
        // feature: S_k = WHT_k @ [x_t | h]^T  (M=128,N=8192,K=256), 512 WGs
        k_gemm<64, 128, 64, 2, 4, 256, 1, 1, 0, 1><<<512, 256, 0, stream>>>(
            WHT, 256, xb, 0, h,
            Sbuf, nullptr, 0, t);
        if (bigws) {
            // graph: Zp[z] = Lcat[:,z*512:+512] @ S[z], split-K=8, 512 WGs,
            // one slice per XCD (DEC=0: bz = id&7)
            k_gemm<128, 128, 8, 8, 8, 512, 3, 0, 512, 0><<<512, 256, 0, stream>>>(
                Lcat, 4096, Sbuf, 4096, nullptr,
                nullptr, Zp, 0, t);
            k_combine<8><<<1024, 256, 0, stream>>>(Zp, h, out, t);
        } else {
            // fallback: single-dispatch graph GEMM (64 WGs, slow but correct)
            k_gemm<128, 128, 8, 8, 1, 4096, 2, 0, 0, 0><<<64, 256, 0, stream>>>(
                Lcat, 4096, Sbuf, 4096, nullptr,
                h, out, 0, t);
        }
    }
}

// Round 6
// 519.398 us; speedup vs baseline: 2.1691x; 1.0761x over previous
//
#include <hip/hip_runtime.h>
#include <stdint.h>

// ---------------------------------------------------------------------------
// RGNN layer: h_t = relu( sum_k L^{k+1} (x_t W_k + h_{t-1} H_k) ), h_{-1}=0
// B=8 T=16 N=1024 F=128 K=4.
//
//   Lcat [1024 n][4096 q],  q=(k,m):  Lcat[n][k*1024+m] = (L^{k+1})[n][m]
//   S    [(b,g) c][4096 q]          : S[c][q] = (x_t W_k + h H_k)[b,m,g]
//   Z[n][c] = sum_q Lcat[n][q] * S[c][q]   (S stored as B^T)
//   h[b][n][g] = relu(Z),  out[b][t][n][g] = h
//
// GEMM: LDS-staged (round-4 register-direct doubled L2 traffic: dead end),
// 32x32x16 MFMA, 3-buffer LDS pipeline with counted vmcnt (loads span
// barriers; never vmcnt(0) in steady state). Graph GEMM split-K=4 with
// 128x64 tiles -> 512 WGs (2 blocks/CU at 72KB LDS), one K-slice per XCD
// pair (~3MB working set, L2-fit). Distinct kernel symbols per flavor for
// profile visibility.
// ---------------------------------------------------------------------------

typedef __bf16 bf16_t;
typedef __bf16 bf16x4 __attribute__((ext_vector_type(4)));
typedef __bf16 bf16x8 __attribute__((ext_vector_type(8)));
typedef float  f32x4  __attribute__((ext_vector_type(4)));
typedef float  f32x16 __attribute__((ext_vector_type(16)));

__device__ __forceinline__ void gload_lds16(const void* g, void* l) {
    __builtin_amdgcn_global_load_lds(
        (const __attribute__((address_space(1))) void*)g,
        (__attribute__((address_space(3))) void*)l,
        16, 0, 0);
}

// ---- setup kernels --------------------------------------------------------

__global__ void k_convert_x(const float* __restrict__ xin,
                            bf16_t* __restrict__ xb, int n4) {
    int i = blockIdx.x * 256 + threadIdx.x;
    int stride = gridDim.x * 256;
    for (; i < n4; i += stride) {
        float4 v = reinterpret_cast<const float4*>(xin)[i];
        bf16x4 o = { (bf16_t)v.x, (bf16_t)v.y, (bf16_t)v.z, (bf16_t)v.w };
        reinterpret_cast<bf16x4*>(xb)[i] = o;
    }
}

__global__ void k_setup_L(const float* __restrict__ L,
                          bf16_t* __restrict__ Lcat,   // [1024][4096], block 0
                          bf16_t* __restrict__ Lt) {   // [1024][1024] = L^T
    int idx = blockIdx.x * 256 + threadIdx.x;          // 1024*1024 threads
    int n = idx >> 10, m = idx & 1023;
    float v = L[idx];
    Lcat[n * 4096 + m] = (bf16_t)v;
    Lt[m * 1024 + n]   = (bf16_t)v;
}

__global__ void k_setup_WH(const float* __restrict__ W,
                           const float* __restrict__ H,
                           bf16_t* __restrict__ WHT) { // [4][128 g][256 f]
    int idx = blockIdx.x * 256 + threadIdx.x;          // 4*128*128 threads
    int k = idx >> 14, f = (idx >> 7) & 127, g = idx & 127;
    WHT[(k * 128 + g) * 256 + f]       = (bf16_t)W[idx];
    WHT[(k * 128 + g) * 256 + 128 + f] = (bf16_t)H[idx];
}

// ---- combine: Z = relu(sum_z Zpart[z]) -> h bf16, out f32 ------------------

__global__ __launch_bounds__(256)
void k_combine(const float* __restrict__ Zp,   // [4][1024][1024] (n, c=(b,g))
               bf16_t* __restrict__ h, float* __restrict__ out, int t) {
    int i = blockIdx.x * 256 + threadIdx.x;    // 262144 threads, 4 f32 each
    int n  = i >> 8;
    int cg = (i & 255) * 4;                    // c base (4-aligned, within b)
    size_t o = (size_t)n * 1024 + cg;
    float4 v0 = *reinterpret_cast<const float4*>(Zp + o);
    float4 v1 = *reinterpret_cast<const float4*>(Zp + 1048576 + o);
    float4 v2 = *reinterpret_cast<const float4*>(Zp + 2097152 + o);
    float4 v3 = *reinterpret_cast<const float4*>(Zp + 3145728 + o);
    float4 s;
    s.x = fmaxf(v0.x + v1.x + v2.x + v3.x, 0.f);
    s.y = fmaxf(v0.y + v1.y + v2.y + v3.y, 0.f);
    s.z = fmaxf(v0.z + v1.z + v2.z + v3.z, 0.f);
    s.w = fmaxf(v0.w + v1.w + v2.w + v3.w, 0.f);
    int b = cg >> 7, g = cg & 127;
    size_t ho = (size_t)b * 131072 + (size_t)n * 128 + g;
    bf16x4 hb = { (bf16_t)s.x, (bf16_t)s.y, (bf16_t)s.z, (bf16_t)s.w };
    *reinterpret_cast<bf16x4*>(h + ho) = hb;
    *reinterpret_cast<float4*>(out + (size_t)b * 2097152
                                   + (size_t)t * 131072
                                   + (size_t)n * 128 + g) = s;
}

// ---- GEMM body (32x32x16 MFMA, 3-buffer counted-vmcnt pipeline) ------------
// C[M][N] = A[M][KTOT] @ B[KTOT][N], B given as B^T rows (N rows, K contig).
// 4 waves 2x2, wave tile (BM/2)x(BN/2), 32x32 fragments. Grid 1D, bijective
// XCD swizzle; DEC=0: x fast / z slow; DEC=1: (y,z) fast / x slow.
// EPI: 0 plain bf16   1 S-layout bf16   2 relu h+out   3 f32 partial Zp[bz]
// BADDR: 0 = BT rows; 1 = feature split x|h.   ZK: per-bz K offset.
template<int BM, int BN, int GX, int GY, int GZ, int KTOT,
         int EPI, int BADDR, int ZK, int DEC>
__device__ __forceinline__
void gemm_body(const bf16_t* __restrict__ A, int lda,
               const bf16_t* __restrict__ BT, int ldbt,
               const bf16_t* __restrict__ B2,
               bf16_t* __restrict__ Cb, float* __restrict__ Cf,
               int ldc, int t)
{
    constexpr int BK = 64;                 // K-tile; LDS rows are 128 B
    constexpr int WM = BM / 2, WN = BN / 2;
    constexpr int MF = WM / 32, NF = WN / 32;
    constexpr int NT = KTOT / BK;          // >= 4 for all instantiations
    constexpr int NWG = GX * GY * GZ;
    constexpr int ACH = BM * 8;            // 16B chunks per A tile
    constexpr int BCH = BN * 8;
    constexpr int LPT = (ACH + BCH) / 256; // gloads per thread per tile

    __shared__ __align__(16) bf16_t As[3][BM * BK];
    __shared__ __align__(16) bf16_t Bs[3][BN * BK];

    const int tid  = threadIdx.x;
    const int lane = tid & 63;
    const int wave = tid >> 6;
    const int wm = wave >> 1, wn = wave & 1;     // 2x2 wave grid

    // bijective XCD swizzle (NWG % 8 == 0)
    const int id  = blockIdx.x;
    const int swz = (id & 7) * (NWG / 8) + (id >> 3);
    int bx, by, bz;
    if (DEC == 0) {
        bx = swz % GX; by = (swz / GX) % GY; bz = swz / (GX * GY);
    } else {
        by = swz % GY; bz = (swz / GY) % GZ; bx = swz / (GY * GZ);
    }

    const int m0 = by * BM;
    const int c0 = bx * BN;
    const int kb_ = bz;                          // tap index OR split-K slice

    const bf16_t* Ap = (EPI == 1) ? (A + kb_ * 128 * 256) : A;

    f32x16 acc[MF][NF] = {};

    auto stage = [&](int bufi, int kt) {
        const int q0 = kt * BK + (ZK > 0 ? kb_ * ZK : 0);
        #pragma unroll
        for (int i = 0; i < ACH / 256; ++i) {
            int chunk = i * 256 + tid;
            int off = chunk * 16;                       // byte off in tile
            int row = off >> 7;                         // 128B rows
            int kel = ((off ^ ((row & 7) << 4)) & 127) >> 1; // inv-swizzled k
            const bf16_t* src = Ap + (size_t)(m0 + row) * lda + (q0 + kel);
            gload_lds16(src, (char*)(&As[bufi][0]) + off);
        }
        #pragma unroll
        for (int i = 0; i < BCH / 256; ++i) {
            int chunk = i * 256 + tid;
            int off = chunk * 16;
            int row = off >> 7;
            int kel = ((off ^ ((row & 7) << 4)) & 127) >> 1;
            int c = c0 + row;
            const bf16_t* src;
            if (BADDR == 0) {
                src = BT + (size_t)c * ldbt + (q0 + kel);
            } else {
                int f = q0 + kel;
                if (q0 < 128) {
                    // x part: xb[B][T][N][F], c=(b,m)
                    src = BT + (size_t)(c >> 10) * 2097152
                             + (size_t)t * 131072
                             + (size_t)(c & 1023) * 128 + f;
                } else {
                    // h part: h[B][N][F] flat, rows are c
                    src = B2 + (size_t)c * 128 + (f - 128);
                }
            }
            gload_lds16(src, (char*)(&Bs[bufi][0]) + off);
        }
    };

    // prologue: tiles 0,1 in flight
    stage(0, 0);
    stage(1, 1);

    for (int kt = 0; kt < NT; ++kt) {
        // wait only the oldest tile; leave next tile's loads in flight
        if (kt < NT - 1) {
            if constexpr (LPT == 4)
                asm volatile("s_waitcnt vmcnt(4)" ::: "memory");
            else if constexpr (LPT == 6)
                asm volatile("s_waitcnt vmcnt(6)" ::: "memory");
            else
                asm volatile("s_waitcnt vmcnt(8)" ::: "memory");
        } else {
            asm volatile("s_waitcnt vmcnt(0)" ::: "memory");
        }
        __builtin_amdgcn_s_barrier();         // tile kt ready; buf[(kt+2)%3]
                                              // free (its readers done)
        __builtin_amdgcn_sched_barrier(0);

        if (kt + 2 < NT) stage((kt + 2) % 3, kt + 2);

        const int cur = kt % 3;
        // 32x32x16 fragments: row=lane&31, k=(lane>>5)*8+j
        #pragma unroll
        for (int kk = 0; kk < 4; ++kk) {
            bf16x8 af[MF], bfr[NF];
            const int klane = kk * 32 + (lane >> 5) * 16;  // byte off of k
            #pragma unroll
            for (int mf = 0; mf < MF; ++mf) {
                int row = wm * WM + mf * 32 + (lane & 31);
                int bo = (row * 128 + klane) ^ ((row & 7) << 4);
                af[mf] = *reinterpret_cast<const bf16x8*>(
                             (const char*)(&As[cur][0]) + bo);
            }
            #pragma unroll
            for (int nf = 0; nf < NF; ++nf) {
                int row = wn * WN + nf * 32 + (lane & 31);
                int bo = (row * 128 + klane) ^ ((row & 7) << 4);
                bfr[nf] = *reinterpret_cast<const bf16x8*>(
                              (const char*)(&Bs[cur][0]) + bo);
            }
            #pragma unroll
            for (int mf = 0; mf < MF; ++mf)
                #pragma unroll
                for (int nf = 0; nf < NF; ++nf)
                    acc[mf][nf] = __builtin_amdgcn_mfma_f32_32x32x16_bf16(
                        af[mf], bfr[nf], acc[mf][nf], 0, 0, 0);
        }
        __builtin_amdgcn_sched_barrier(0);
    }

    // epilogue: 32x32 D map col=lane&31, row=(r&3)+8*(r>>2)+4*(lane>>5)
    #pragma unroll
    for (int mf = 0; mf < MF; ++mf) {
        #pragma unroll
        for (int nf = 0; nf < NF; ++nf) {
            f32x16 v = acc[mf][nf];
            int col   = c0 + wn * WN + nf * 32 + (lane & 31);
            int rbase = m0 + wm * WM + mf * 32 + 4 * (lane >> 5);
            #pragma unroll
            for (int r = 0; r < 16; ++r) {
                int row = rbase + (r & 3) + 8 * (r >> 2);
                float val = v[r];
                if (EPI == 0) {
                    Cb[(size_t)row * ldc + col] = (bf16_t)val;
                } else if (EPI == 1) {
                    // S[b][g][k][m]: col=(b,m), row=g
                    Cb[(size_t)(col >> 10) * 524288 + (size_t)row * 4096
                       + (size_t)kb_ * 1024 + (col & 1023)] = (bf16_t)val;
                } else if (EPI == 2) {
                    val = fmaxf(val, 0.f);
                    int b = col >> 7, g = col & 127;   // col=(b,g), row=n
                    Cb[(size_t)b * 131072 + (size_t)row * 128 + g] = (bf16_t)val;
                    Cf[(size_t)b * 2097152 + (size_t)t * 131072
                       + (size_t)row * 128 + g] = val;
                } else {
                    // f32 partial: Zpart[kb_][row n][col c]
                    Cf[(size_t)kb_ * 1048576 + (size_t)row * 1024 + col] = val;
                }
            }
        }
    }
}

// ---- flavor wrappers (distinct symbols for rocprof) ------------------------

__global__ __launch_bounds__(256)
void k_chain(const bf16_t* __restrict__ A, const bf16_t* __restrict__ BT,
             bf16_t* __restrict__ Cb) {
    // M=N=K=1024, 64x64 tiles, grid 256
    gemm_body<64, 64, 16, 16, 1, 1024, 0, 0, 0, 0>(
        A, 4096, BT, 1024, nullptr, Cb, nullptr, 4096, 0);
}

__global__ __launch_bounds__(256)
void k_feat(const bf16_t* __restrict__ WHT, const bf16_t* __restrict__ xb,
            const bf16_t* __restrict__ h, bf16_t* __restrict__ Sbuf, int t) {
    // M=128,N=8192,K=256 per tap; 64x128 tiles, grid 512
    gemm_body<64, 128, 64, 2, 4, 256, 1, 1, 0, 1>(
        WHT, 256, xb, 0, h, Sbuf, nullptr, 0, t);
}

__global__ __launch_bounds__(256)
void k_graph(const bf16_t* __restrict__ Lcat, const bf16_t* __restrict__ Sbuf,
             float* __restrict__ Zp) {
    // M=1024,N=1024, split-K=4 (K=1024/slice); 128x64 tiles, grid 512
    gemm_body<128, 64, 16, 8, 4, 1024, 3, 0, 1024, 0>(
        Lcat, 4096, Sbuf, 4096, nullptr, nullptr, Zp, 0, 0);
}

__global__ __launch_bounds__(256)
void k_graph_ns(const bf16_t* __restrict__ Lcat, const bf16_t* __restrict__ Sbuf,
                bf16_t* __restrict__ h, float* __restrict__ out, int t) {
    // fallback: no split-K, K=4096; 128x128 tiles, grid 64
    gemm_body<128, 128, 8, 8, 1, 4096, 2, 0, 0, 0>(
        Lcat, 4096, Sbuf, 4096, nullptr, h, out, 0, t);
}

// ---- launch ---------------------------------------------------------------

extern "C" void kernel_launch(void* const* d_in, const int* in_sizes, int n_in,
                              void* d_out, int out_size, void* d_ws, size_t ws_size,
                              hipStream_t stream) {
    const float* x = (const float*)d_in[0];   // [8][16][1024][128]
    const float* L = (const float*)d_in[1];   // [1024][1024]
    const float* W = (const float*)d_in[2];   // [4][128][128]
    const float* H = (const float*)d_in[3];   // [4][128][128]
    float* out = (float*)d_out;               // [8][16][1024][128]

    char* ws = (char*)d_ws;
    bf16_t* xb   = (bf16_t*)(ws);              // 33,554,432 B
    bf16_t* Lcat = (bf16_t*)(ws + 33554432);   //  8,388,608 B [1024][4096]
    bf16_t* Lt   = (bf16_t*)(ws + 41943040);   //  2,097,152 B
    bf16_t* WHT  = (bf16_t*)(ws + 44040192);   //    262,144 B
    bf16_t* Sbuf = (bf16_t*)(ws + 44302336);   //  8,388,608 B [1024][4096]
    bf16_t* h    = (bf16_t*)(ws + 52690944);   //  2,097,152 B [8][1024][128]
    float*  Zp   = (float*) (ws + 54788096);   // 16,777,216 B [4][1024][1024]
    if (ws_size < 54788096u) return;
    const bool bigws = (ws_size >= 71565312u);

    hipMemsetAsync(h, 0, 2097152, stream);
    k_convert_x<<<4096, 256, 0, stream>>>(x, xb, 16777216 / 4);
    k_setup_L <<<4096, 256, 0, stream>>>(L, Lcat, Lt);
    k_setup_WH<<<256, 256, 0, stream>>>(W, H, WHT);

    // L-power chain: block p = block(p-1) @ L (M=N=K=1024), 256 WGs
    for (int p = 1; p < 4; ++p) {
        k_chain<<<256, 256, 0, stream>>>(Lcat + (p - 1) * 1024, Lt,
                                         Lcat + p * 1024);
    }

    for (int t = 0; t < 16; ++t) {
        // feature: S_k = WHT_k @ [x_t | h]^T  (M=128,N=8192,K=256), 512 WGs
        k_feat<<<512, 256, 0, stream>>>(WHT, xb, h, Sbuf, t);
        if (bigws) {
            // graph: Zp[z] = Lcat[:,z*1024:+1024] @ S[z], split-K=4, 512 WGs
            k_graph<<<512, 256, 0, stream>>>(Lcat, Sbuf, Zp);
            k_combine<<<1024, 256, 0, stream>>>(Zp, h, out, t);
        } else {
            k_graph_ns<<<64, 256, 0, stream>>>(Lcat, Sbuf, h, out, t);
        }
    }
}